// Round 7
// baseline (304.319 us; speedup 1.0000x reference)
//
#include <hip/hip_runtime.h>
#include <hip/hip_fp16.h>
#include <math.h>

#define CDIM 256
#define NE   1024
#define HW   4096            // 64*64
#define NB   16
#define ZQ_SIZE (NB*CDIM*HW) // 16777216

typedef unsigned short ushort_t;
typedef __attribute__((ext_vector_type(8))) _Float16 f16x8;
typedef __attribute__((ext_vector_type(8))) unsigned short u16x8;
typedef __attribute__((ext_vector_type(4))) float f32x4;

#define AS1 __attribute__((address_space(1)))
#define AS3 __attribute__((address_space(3)))

// fp16 1-pass dot error: z*(e-e16) rms ~1.3e-6, e16*(z-z16) rms ~1.3e-6
// -> sigma(dot) ~1.8e-6, sigma(d-gap) ~5.2e-6. 6e-5 >= 11 sigma. Safe.
#define MARGIN 6.0e-5f

// ws layout (bytes)
#define WS_EE    0           // 1024 f32
#define WS_ZZ    4096        // 65536 f32
#define WS_CNT   266240      // 1 int (+pad)
#define WS_LIST  266496      // 65536 int
#define WS_ESWZ  528640      // 16 slabs x 32768 B fp16 fragment-major
#define WS_NEEDED 1052928

// ---------------- helpers (validated rounds 1-6) ----------------
__device__ __forceinline__ float sq_nofma(float v) {
    float v2 = v * v;
    asm volatile("" : "+v"(v2));
    return v2;
}

template <typename F>
__device__ __forceinline__ float pairwise256_sq(F get) {
    float total = 0.0f;
    #pragma unroll
    for (int h = 0; h < 2; ++h) {
        float r[8];
        #pragma unroll
        for (int j = 0; j < 8; ++j) r[j] = sq_nofma(get(h * 128 + j));
        #pragma unroll
        for (int i = 8; i < 128; i += 8) {
            #pragma unroll
            for (int j = 0; j < 8; ++j) r[j] += sq_nofma(get(h * 128 + i + j));
        }
        float s = ((r[0] + r[1]) + (r[2] + r[3])) + ((r[4] + r[5]) + (r[6] + r[7]));
        total = (h == 0) ? s : (total + s);
    }
    return total;
}

template <typename F>
__device__ __forceinline__ float pairwise128_sq(F get) {
    float r[8];
    #pragma unroll
    for (int j = 0; j < 8; ++j) r[j] = sq_nofma(get(j));
    #pragma unroll
    for (int i = 8; i < 128; i += 8) {
        #pragma unroll
        for (int j = 0; j < 8; ++j) r[j] += sq_nofma(get(i + j));
    }
    return ((r[0] + r[1]) + (r[2] + r[3])) + ((r[4] + r[5]) + (r[6] + r[7]));
}

__device__ __forceinline__ ushort_t f2h(float v) {
    return __half_as_ushort(__float2half(v));   // v_cvt_f16_f32, RNE
}

// ||emb_j||^2 -> ws (standalone; used only by the legacy path)
__global__ __launch_bounds__(256) void ee_kernel(const float* __restrict__ emb,
                                                 float* __restrict__ ee,
                                                 int* __restrict__ cnt) {
    if (blockIdx.x == 0 && threadIdx.x == 0) *cnt = 0;
    int j = blockIdx.x * 256 + threadIdx.x;
    const float* row = emb + (size_t)j * CDIM;
    ee[j] = pairwise256_sq([&](int i) { return row[i]; });
}

// merged: blocks 0..127 = emb fp32->fp16 fragment-major; blocks 128..131 = ee
__global__ __launch_bounds__(256) void ecvt_kernel(const float* __restrict__ emb,
                                                   ushort_t* __restrict__ eswz,
                                                   float* __restrict__ ee,
                                                   int* __restrict__ cnt) {
    if (blockIdx.x >= 128) {
        if (blockIdx.x == 128 && threadIdx.x == 0) *cnt = 0;
        int j = (blockIdx.x - 128) * 256 + threadIdx.x;
        const float* row = emb + (size_t)j * CDIM;
        ee[j] = pairwise256_sq([&](int i) { return row[i]; });
        return;
    }
    int g = blockIdx.x * 256 + threadIdx.x;   // 32768 threads
    int s  = g >> 11;          // slab
    int r  = g & 2047;
    int cw = r >> 3;           // code within chunk 0..255
    int kg = r & 7;            // k-group of 8 within slab
    int chunk = s >> 2, kb = s & 3;
    int wn = cw >> 5, n = (cw >> 4) & 1, lr = cw & 15;
    int ks = kg >> 2, lg = kg & 3;

    const float* src = emb + (size_t)(chunk * 256 + cw) * CDIM + kb * 64 + kg * 8;
    float4 a = *reinterpret_cast<const float4*>(src);
    float4 b = *reinterpret_cast<const float4*>(src + 4);
    u16x8 p = { f2h(a.x), f2h(a.y), f2h(a.z), f2h(a.w),
                f2h(b.x), f2h(b.y), f2h(b.z), f2h(b.w) };
    int f = (wn * 2 + ks) * 2 + n;
    size_t dst = (size_t)s * 32768 + f * 1024 + (lg * 16 + lr) * 16;
    *reinterpret_cast<u16x8*>((char*)eswz + dst) = p;
}

// ---------------- main MFMA kernel: 512 thr, 8 waves, 64 tokens ----------------
// z A-fragments held in registers (128 VGPR); E slab double-buffered with
// issue-early / vmcnt(0)-late prefetch (T3 2-phase).
__global__ __launch_bounds__(512, 2) void vq_main(const float* __restrict__ z,
                                                  const float* __restrict__ emb,
                                                  const ushort_t* __restrict__ eswz,
                                                  const float* __restrict__ eew,
                                                  float* __restrict__ zzw,
                                                  int* __restrict__ cnt,
                                                  int* __restrict__ list,
                                                  float* __restrict__ out) {
    __shared__ __align__(16) char arena[109312];
    char*  zfB = arena;                     // 32768: z fp16 fragment-major
    char*  esB = arena + 32768;             // 2 x 32768: E slab double-buffer
    float* eel = (float*)(arena + 98304);   // 1024 f32
    float* zzp = (float*)(arena + 102400);  // 64x2 f32 halves
    float* rd1 = (float*)(arena + 102912);  // [8][64]
    int*   rj1 = (int*)  (arena + 104960);
    float* rd2 = (float*)(arena + 107008);
    int*   rbj = (int*)  (arena + 109056);  // 64

    const int tid  = threadIdx.x;
    const int lane = tid & 63;
    const int wn   = tid >> 6;              // wave 0..7
    const int b    = blockIdx.x >> 6;
    const int hw0  = (blockIdx.x & 63) << 6;
    const float* zb = z + (size_t)b * CDIM * HW + hw0;
    const int lr = lane & 15;
    const int lg = lane >> 4;
    const int laneoff = lane << 4;

    // ---- issue slab-0 DMA first (latency hides under z staging) ----
    {
        const char* gsrc = (const char*)eswz;
        #pragma unroll
        for (int q = 0; q < 4; ++q)
            __builtin_amdgcn_global_load_lds(
                (const AS1 unsigned*)(gsrc + (q << 13) + (tid << 4)),
                (AS3 unsigned*)(esB + (q << 13) + (wn << 10)), 16, 0, 0);
    }

    // ---- prologue: z -> fp16 frag-major, eel, zz halves ----
    {
        const int tok = lane;
        #pragma unroll
        for (int i = 0; i < 4; ++i) {
            int kg = (wn << 2) + i;          // 0..31
            int k0 = kg << 3;
            u16x8 p;
            #pragma unroll
            for (int e = 0; e < 8; ++e)
                p[e] = f2h(zb[(size_t)(k0 + e) * HW + tok]);
            int m = tok >> 4, lrr = tok & 15;
            int kb_ = kg >> 3, ks_ = (kg >> 2) & 1, lg_ = kg & 3;
            int off = (((kb_ * 2 + ks_) * 4 + m) << 10) + ((lg_ * 16 + lrr) << 4);
            *(u16x8*)(zfB + off) = p;
        }
        eel[tid]       = eew[tid];
        eel[tid + 512] = eew[tid + 512];
    }
    if (tid < 128) {   // exact numpy-pairwise halves
        int tok = tid >> 1, h = tid & 1;
        zzp[tok * 2 + h] = pairwise128_sq([&](int i) {
            return zb[(size_t)(h * 128 + i) * HW + tok];
        });
    }
    asm volatile("s_waitcnt vmcnt(0)" ::: "memory");
    __syncthreads();

    // ---- all 32 z A-frags -> registers (read zfB once) ----
    f16x8 ah[32];
    #pragma unroll
    for (int f = 0; f < 32; ++f)
        ah[f] = *(const f16x8*)(zfB + (f << 10) + laneoff);

    f32x4 acc[4][2];
    float sd1[4][4], sd2[4][4];
    int   sj1[4][4];
    #pragma unroll
    for (int m = 0; m < 4; ++m)
        #pragma unroll
        for (int r = 0; r < 4; ++r) { sd1[m][r] = INFINITY; sd2[m][r] = INFINITY; sj1[m][r] = NE; }

    #pragma unroll
    for (int s = 0; s < 16; ++s) {
        const int chunk = s >> 2, kb = s & 3;
        const char* bufc = esB + ((s & 1) << 15);
        // issue slab s+1 into the other buffer (free since last barrier)
        if (s < 15) {
            const char* gsrc = (const char*)eswz + (size_t)(s + 1) * 32768;
            char* dstb = esB + (((s + 1) & 1) << 15);
            #pragma unroll
            for (int q = 0; q < 4; ++q)
                __builtin_amdgcn_global_load_lds(
                    (const AS1 unsigned*)(gsrc + (q << 13) + (tid << 4)),
                    (AS3 unsigned*)(dstb + (q << 13) + (wn << 10)), 16, 0, 0);
        }
        if (kb == 0) {
            #pragma unroll
            for (int m = 0; m < 4; ++m)
                #pragma unroll
                for (int n = 0; n < 2; ++n) acc[m][n] = (f32x4){0.f, 0.f, 0.f, 0.f};
        }
        #pragma unroll
        for (int ks = 0; ks < 2; ++ks) {
            f16x8 bh[2];
            #pragma unroll
            for (int n = 0; n < 2; ++n)
                bh[n] = *(const f16x8*)(bufc + (((wn * 2 + ks) * 2 + n) << 10) + laneoff);
            #pragma unroll
            for (int m = 0; m < 4; ++m)
                #pragma unroll
                for (int n = 0; n < 2; ++n)
                    acc[m][n] = __builtin_amdgcn_mfma_f32_16x16x32_f16(
                        ah[(kb * 2 + ks) * 4 + m], bh[n], acc[m][n], 0, 0, 0);
        }
        if (kb == 3) {   // chunk epilogue: d = fl(fl(zz+ee) - fl(2*dot)), top-2
            #pragma unroll
            for (int m = 0; m < 4; ++m)
                #pragma unroll
                for (int r = 0; r < 4; ++r) {
                    int t = m * 16 + lg * 4 + r;
                    float zzv = zzp[2 * t] + zzp[2 * t + 1];
                    #pragma unroll
                    for (int n = 0; n < 2; ++n) {
                        int code = (chunk << 8) + (wn << 5) + (n << 4) + lr;
                        float t1 = zzv + eel[code];
                        float d  = t1 - 2.0f * acc[m][n][r];
                        bool lt1 = d < sd1[m][r];
                        bool lt2 = d < sd2[m][r];
                        sd2[m][r] = lt1 ? sd1[m][r] : (lt2 ? d : sd2[m][r]);
                        if (lt1) { sd1[m][r] = d; sj1[m][r] = code; }
                    }
                }
        }
        asm volatile("s_waitcnt vmcnt(0)" ::: "memory");   // slab s+1 landed
        __syncthreads();
    }

    // ---- cross-lane top-2 merge over the 16 code-lanes ----
    #pragma unroll
    for (int off = 1; off <= 8; off <<= 1) {
        #pragma unroll
        for (int m = 0; m < 4; ++m)
            #pragma unroll
            for (int r = 0; r < 4; ++r) {
                float od1 = __shfl_xor(sd1[m][r], off);
                int   oj1 = __shfl_xor(sj1[m][r], off);
                float od2 = __shfl_xor(sd2[m][r], off);
                float nd2 = fminf(fmaxf(sd1[m][r], od1), fminf(sd2[m][r], od2));
                bool tk = (od1 < sd1[m][r]) || (od1 == sd1[m][r] && oj1 < sj1[m][r]);
                if (tk) { sd1[m][r] = od1; sj1[m][r] = oj1; }
                sd2[m][r] = nd2;
            }
    }
    if (lr == 0) {
        #pragma unroll
        for (int m = 0; m < 4; ++m)
            #pragma unroll
            for (int r = 0; r < 4; ++r) {
                int tok = m * 16 + lg * 4 + r;
                rd1[wn * 64 + tok] = sd1[m][r];
                rj1[wn * 64 + tok] = sj1[m][r];
                rd2[wn * 64 + tok] = sd2[m][r];
            }
    }
    __syncthreads();

    // ---- combine 8 waves, decide, emit idx / flag / zz ----
    if (tid < 64) {
        float d1f = rd1[tid]; int j1f = rj1[tid]; float d2f = rd2[tid];
        #pragma unroll
        for (int w = 1; w < 8; ++w) {
            float od1 = rd1[w * 64 + tid];
            int   oj1 = rj1[w * 64 + tid];
            float od2 = rd2[w * 64 + tid];
            float nd2 = fminf(fmaxf(d1f, od1), fminf(d2f, od2));
            bool tk = (od1 < d1f) || (od1 == d1f && oj1 < j1f);
            if (tk) { d1f = od1; j1f = oj1; }
            d2f = nd2;
        }
        rbj[tid] = j1f;
        int gtok = b * HW + hw0 + tid;
        out[(size_t)ZQ_SIZE + gtok] = (float)j1f;
        zzw[gtok] = zzp[2 * tid] + zzp[2 * tid + 1];
        if (!(d2f - d1f > MARGIN)) {
            int slot = atomicAdd(cnt, 1);
            list[slot] = gtok;
        }
    }
    __syncthreads();

    // ---- z_q: gather emb rows -> LDS -> coalesced NCHW ----
    float* zq_st = (float*)arena;   // [64][260] = 66560 B (aliases zfB/esB)
    {
        int row = tid >> 3, sub = tid & 7;
        int j = rbj[row];
        const float* er = emb + (size_t)j * CDIM;
        #pragma unroll
        for (int i = 0; i < 8; ++i) {
            int c = (sub << 2) + (i << 5);
            float4 v = *reinterpret_cast<const float4*>(er + c);
            *reinterpret_cast<float4*>(&zq_st[row * 260 + c]) = v;
        }
    }
    __syncthreads();
    {
        int tok = tid & 63, cg = tid >> 6;
        float* ob = out + (size_t)b * CDIM * HW + hw0 + tok;
        #pragma unroll 4
        for (int i = 0; i < 32; ++i) {
            int c = (cg << 5) + i;
            ob[(size_t)c * HW] = zq_st[tok * 260 + c];
        }
    }
}

// ---------------- exact fp32 fallback: 8 waves, 8 tokens per staged chunk ----------------
__global__ __launch_bounds__(512) void vq_fallback(const float* __restrict__ z,
                                                   const float* __restrict__ emb,
                                                   const float* __restrict__ eew,
                                                   const float* __restrict__ zzw,
                                                   const int* __restrict__ cnt,
                                                   const int* __restrict__ list,
                                                   float* __restrict__ out) {
    __shared__ __align__(16) float elds[64 * 260];
    __shared__ float zrow[8][256];
    __shared__ int   toks[8];

    const int tid  = threadIdx.x;
    const int lane = tid & 63;
    const int wv   = tid >> 6;           // 8 waves
    const int nt   = *cnt;
    const int groups = (nt + 7) >> 3;

    for (int g = blockIdx.x; g < groups; g += gridDim.x) {
        if (tid < 8) toks[tid] = (g * 8 + tid < nt) ? list[g * 8 + tid] : -1;
        __syncthreads();
        const int gt  = toks[wv];
        const bool act = gt >= 0;
        const int tb  = act ? (gt >> 12) : 0;
        const int thw = act ? (gt & 4095) : 0;
        if (act) {
            #pragma unroll
            for (int i = 0; i < 4; ++i)
                zrow[wv][i * 64 + lane] = z[(size_t)tb * CDIM * HW + (size_t)(i * 64 + lane) * HW + thw];
        }
        const float zz = act ? zzw[gt] : 0.0f;
        float d1 = INFINITY; int j1 = NE;

        for (int c = 0; c < 16; ++c) {
            __syncthreads();
            {   // stage 64 codes x 256 dims with 512 threads
                int row = tid >> 3, sub = tid & 7;
                #pragma unroll
                for (int i = 0; i < 8; ++i) {
                    int col = (sub << 2) + (i << 5);
                    float4 v = *reinterpret_cast<const float4*>(
                        &emb[(size_t)(c * 64 + row) * CDIM + col]);
                    *reinterpret_cast<float4*>(&elds[row * 260 + col]) = v;
                }
            }
            __syncthreads();
            if (act) {
                float acc = 0.0f;
                #pragma unroll 8
                for (int kq = 0; kq < 64; ++kq) {
                    float4 ev = *reinterpret_cast<const float4*>(&elds[lane * 260 + kq * 4]);
                    float4 zv = *reinterpret_cast<const float4*>(&zrow[wv][kq * 4]);
                    acc = fmaf(zv.x, ev.x, acc);
                    acc = fmaf(zv.y, ev.y, acc);
                    acc = fmaf(zv.z, ev.z, acc);
                    acc = fmaf(zv.w, ev.w, acc);
                }
                int j = c * 64 + lane;
                float t1 = zz + eew[j];
                float d  = t1 - 2.0f * acc;
                if (d < d1) { d1 = d; j1 = j; }
            }
        }
        #pragma unroll
        for (int off = 1; off <= 32; off <<= 1) {
            float od = __shfl_xor(d1, off);
            int   oj = __shfl_xor(j1, off);
            if (od < d1 || (od == d1 && oj < j1)) { d1 = od; j1 = oj; }
        }
        if (act) {
            if (lane == 0) out[(size_t)ZQ_SIZE + gt] = (float)j1;
            #pragma unroll
            for (int i = 0; i < 4; ++i) {
                int cc = i * 64 + lane;
                out[(size_t)tb * CDIM * HW + (size_t)cc * HW + thw] = emb[(size_t)j1 * CDIM + cc];
            }
        }
        __syncthreads();
    }
}

// ---------------- legacy round-1 kernel (only if ws too small) ----------------
#define BM 32
#define BN 256
#define BK 16
__global__ __launch_bounds__(256, 3) void vq_legacy(const float* __restrict__ z,
                                                    const float* __restrict__ emb,
                                                    const float* __restrict__ ee,
                                                    float* __restrict__ out) {
    __shared__ float zs[CDIM][BM];
    __shared__ float es[BK][BN];
    __shared__ float ees[BN];
    __shared__ float zzs[BM];
    __shared__ float red_d[4][BM];
    __shared__ int   red_j[4][BM];
    __shared__ int   bestj_s[BM];

    const int tid = threadIdx.x;
    const int b   = blockIdx.x >> 7;
    const int hw0 = (blockIdx.x & 127) << 5;
    const int ti  = tid & 7;
    const int tj  = tid >> 3;
    const int tm0 = ti << 2;
    const int jc0 = tj << 3;
    {
        const float* zb = z + (size_t)b * CDIM * HW + hw0;
        #pragma unroll
        for (int r = 0; r < 8; ++r) {
            int f4 = (r << 8) + tid;
            int c  = f4 >> 3;
            int t4 = (f4 & 7) << 2;
            float4 v = *reinterpret_cast<const float4*>(zb + (size_t)c * HW + t4);
            *reinterpret_cast<float4*>(&zs[c][t4]) = v;
        }
    }
    __syncthreads();
    if (tid < BM) zzs[tid] = pairwise256_sq([&](int i) { return zs[i][tid]; });
    __syncthreads();
    float bd[4]; int bj[4];
    #pragma unroll
    for (int i = 0; i < 4; ++i) { bd[i] = INFINITY; bj[i] = NE; }
    for (int jt = 0; jt < NE / BN; ++jt) {
        const int j0 = jt * BN;
        float acc[4][8];
        #pragma unroll
        for (int i = 0; i < 4; ++i)
            #pragma unroll
            for (int jj = 0; jj < 8; ++jj) acc[i][jj] = 0.0f;
        for (int kt = 0; kt < CDIM / BK; ++kt) {
            __syncthreads();
            #pragma unroll
            for (int r = 0; r < 4; ++r) {
                int f4 = (r << 8) + tid;
                int jj = f4 >> 2;
                int c4 = (f4 & 3) << 2;
                float4 v = *reinterpret_cast<const float4*>(
                    emb + (size_t)(j0 + jj) * CDIM + kt * BK + c4);
                es[c4 + 0][jj] = v.x; es[c4 + 1][jj] = v.y;
                es[c4 + 2][jj] = v.z; es[c4 + 3][jj] = v.w;
            }
            if (kt == 0 && tid < BN) ees[tid] = ee[j0 + tid];
            __syncthreads();
            #pragma unroll
            for (int k = 0; k < BK; ++k) {
                float4 av  = *reinterpret_cast<const float4*>(&zs[kt * BK + k][tm0]);
                float4 bv0 = *reinterpret_cast<const float4*>(&es[k][jc0]);
                float4 bv1 = *reinterpret_cast<const float4*>(&es[k][jc0 + 4]);
                float bb[8] = {bv0.x, bv0.y, bv0.z, bv0.w, bv1.x, bv1.y, bv1.z, bv1.w};
                #pragma unroll
                for (int jj = 0; jj < 8; ++jj) {
                    acc[0][jj] = fmaf(av.x, bb[jj], acc[0][jj]);
                    acc[1][jj] = fmaf(av.y, bb[jj], acc[1][jj]);
                    acc[2][jj] = fmaf(av.z, bb[jj], acc[2][jj]);
                    acc[3][jj] = fmaf(av.w, bb[jj], acc[3][jj]);
                }
            }
        }
        #pragma unroll
        for (int i = 0; i < 4; ++i) {
            float zzv = zzs[tm0 + i];
            #pragma unroll
            for (int jj = 0; jj < 8; ++jj) {
                float t1 = zzv + ees[jc0 + jj];
                float d  = t1 - 2.0f * acc[i][jj];
                if (d < bd[i]) { bd[i] = d; bj[i] = j0 + jc0 + jj; }
            }
        }
    }
    #pragma unroll
    for (int off = 8; off <= 32; off <<= 1) {
        #pragma unroll
        for (int i = 0; i < 4; ++i) {
            float od = __shfl_xor(bd[i], off);
            int   oj = __shfl_xor(bj[i], off);
            if (od < bd[i] || (od == bd[i] && oj < bj[i])) { bd[i] = od; bj[i] = oj; }
        }
    }
    {
        const int lane = tid & 63;
        const int w    = tid >> 6;
        if (lane < 8) {
            #pragma unroll
            for (int i = 0; i < 4; ++i) {
                red_d[w][lane * 4 + i] = bd[i];
                red_j[w][lane * 4 + i] = bj[i];
            }
        }
    }
    __syncthreads();
    if (tid < BM) {
        float d = red_d[0][tid]; int j = red_j[0][tid];
        #pragma unroll
        for (int w2 = 1; w2 < 4; ++w2) {
            float od = red_d[w2][tid]; int oj = red_j[w2][tid];
            if (od < d || (od == d && oj < j)) { d = od; j = oj; }
        }
        bestj_s[tid] = j;
        out[(size_t)ZQ_SIZE + (size_t)b * HW + hw0 + tid] = (float)j;
    }
    __syncthreads();
    {
        const int t  = tid & 31;
        const int c0 = tid >> 5;
        const int jb = bestj_s[t];
        const float* er = emb + (size_t)jb * CDIM;
        float* ob = out + (size_t)b * CDIM * HW + hw0 + t;
        #pragma unroll
        for (int c = c0; c < CDIM; c += 8) ob[(size_t)c * HW] = er[c];
    }
}

extern "C" void kernel_launch(void* const* d_in, const int* in_sizes, int n_in,
                              void* d_out, int out_size, void* d_ws, size_t ws_size,
                              hipStream_t stream) {
    const float* z   = (const float*)d_in[0];
    const float* emb = (const float*)d_in[1];
    float* out = (float*)d_out;
    char*  ws  = (char*)d_ws;

    float*    ee   = (float*)(ws + WS_EE);
    float*    zzw  = (float*)(ws + WS_ZZ);
    int*      cnt  = (int*)  (ws + WS_CNT);
    int*      list = (int*)  (ws + WS_LIST);
    ushort_t* eswz = (ushort_t*)(ws + WS_ESWZ);

    if (ws_size >= (size_t)WS_NEEDED) {
        ecvt_kernel<<<dim3(132), dim3(256), 0, stream>>>(emb, eswz, ee, cnt);
        vq_main<<<dim3((NB * HW) / 64), dim3(512), 0, stream>>>(z, emb, eswz, ee, zzw,
                                                                cnt, list, out);
        vq_fallback<<<dim3(128), dim3(512), 0, stream>>>(z, emb, ee, zzw, cnt, list, out);
    } else {
        ee_kernel<<<dim3(NE / 256), dim3(256), 0, stream>>>(emb, ee, cnt);
        vq_legacy<<<dim3((NB * HW) / BM), dim3(256), 0, stream>>>(z, emb, ee, out);
    }
}